// Round 10
// baseline (297.586 us; speedup 1.0000x reference)
//
#include <hip/hip_runtime.h>
#include <hip/hip_bf16.h>

#define BIGV 1.0e9f

static constexpr int B_ = 32;
static constexpr int L_ = 1024;
static constexpr int F_ = 128;
static constexpr int UDIM_ = 1536;   // skewed u-rows (max used 1527; loader reads <=1535)
static constexpr int NPH_ = 96;      // phases; 2 macros each; macros 0..190
static constexpr size_t STREAM_US = (size_t)B_ * UDIM_ * 1024;  // ushorts

typedef __attribute__((ext_vector_type(8))) short short8;
typedef __attribute__((ext_vector_type(4))) float f32x4;

__device__ __forceinline__ unsigned pack2(float x, float y) {
  union { float f; unsigned u; } a, b;
  a.f = x; b.f = y;
  unsigned lo = (a.u + 0x7FFFu + ((a.u >> 16) & 1u)) >> 16;
  unsigned hi = (b.u + 0x7FFFu + ((b.u >> 16) & 1u)) >> 16;
  return lo | (hi << 16);
}

// one wave per row of 128 floats; nrm[wid] = sum of squares
__global__ void norm_kernel(const float* __restrict__ s1, const float* __restrict__ s2,
                            float* __restrict__ nrm) {
  int gt   = blockIdx.x * blockDim.x + threadIdx.x;
  int wid  = gt >> 6;
  int lane = gt & 63;
  const float* src = (wid < B_ * L_) ? (s1 + (size_t)wid * F_)
                                     : (s2 + (size_t)(wid - B_ * L_) * F_);
  float2 v = ((const float2*)src)[lane];
  float s = v.x * v.x + v.y * v.y;
#pragma unroll
  for (int o = 32; o > 0; o >>= 1) s += __shfl_xor(s, o, 64);
  if (lane == 0) nrm[wid] = s;
}

// cost matrix -> bf16, one skewed stream per batch:
// element (row r, col c) stored at stream[b][u = c + 8*(r>>4)][r].
// dtw lane l (rows 16l..16l+15) at macro m reads u-rows 8m..8m+7 at [16l..16l+15]:
// 32 B contiguous per lane per u-row.
__global__ __launch_bounds__(256) void cost_kernel(const float* __restrict__ s1,
                                                   const float* __restrict__ s2,
                                                   ushort* __restrict__ stream,
                                                   const float* __restrict__ nrm) {
  __shared__ short aL[128][136];
  __shared__ short bL[128][136];
  __shared__ float q1[128], q2[128];

  const int tid = threadIdx.x;
  const int b   = blockIdx.y;
  const int tc  = blockIdx.x & 7;
  const int tr  = blockIdx.x >> 3;

  const float* Ap = s1 + (size_t)b * L_ * F_ + (size_t)tr * 128 * F_;
  const float* Bp = s2 + (size_t)b * L_ * F_ + (size_t)tc * 128 * F_;

#pragma unroll 4
  for (int it = 0; it < 16; ++it) {
    int idx = it * 1024 + tid * 4;
    int r = idx >> 7, cc = idx & 127;
    float4 va = *(const float4*)(Ap + idx);
    float4 vb = *(const float4*)(Bp + idx);
    *(uint2*)&aL[r][cc] = make_uint2(pack2(va.x, va.y), pack2(va.z, va.w));
    *(uint2*)&bL[r][cc] = make_uint2(pack2(vb.x, vb.y), pack2(vb.z, vb.w));
  }
  if (tid < 128) q1[tid] = nrm[(size_t)b * L_ + tr * 128 + tid];
  else           q2[tid - 128] = nrm[(size_t)B_ * L_ + (size_t)b * L_ + tc * 128 + (tid - 128)];
  __syncthreads();

  const int wave = tid >> 6, lane = tid & 63, quad = lane >> 4, l16 = lane & 15;
  const int m0 = (wave >> 1) * 64, n0 = (wave & 1) * 64;

  f32x4 acc[4][4] = {};
#pragma unroll
  for (int kc = 0; kc < 4; ++kc) {
    short8 af[4], bf[4];
#pragma unroll
    for (int mi = 0; mi < 4; ++mi)
      af[mi] = *(const short8*)&aL[m0 + mi * 16 + l16][kc * 32 + quad * 8];
#pragma unroll
    for (int nj = 0; nj < 4; ++nj)
      bf[nj] = *(const short8*)&bL[n0 + nj * 16 + l16][kc * 32 + quad * 8];
#pragma unroll
    for (int mi = 0; mi < 4; ++mi)
#pragma unroll
      for (int nj = 0; nj < 4; ++nj)
        acc[mi][nj] = __builtin_amdgcn_mfma_f32_16x16x32_bf16(af[mi], bf[nj], acc[mi][nj], 0, 0, 0);
  }

  ushort* Sb = stream + (size_t)b * UDIM_ * 1024;
#pragma unroll
  for (int mi = 0; mi < 4; ++mi)
#pragma unroll
    for (int nj = 0; nj < 4; ++nj) {
      int lr0 = m0 + mi * 16 + quad * 4;
      int lc  = n0 + nj * 16 + l16;
      int r0  = tr * 128 + lr0;   // 4-aligned: rows r0..r0+3 share (r>>4)
      int c   = tc * 128 + lc;
      float vx = sqrtf(fmaxf(q1[lr0 + 0] + q2[lc] - 2.0f * acc[mi][nj][0], 0.0f));
      float vy = sqrtf(fmaxf(q1[lr0 + 1] + q2[lc] - 2.0f * acc[mi][nj][1], 0.0f));
      float vz = sqrtf(fmaxf(q1[lr0 + 2] + q2[lc] - 2.0f * acc[mi][nj][2], 0.0f));
      float vw = sqrtf(fmaxf(q1[lr0 + 3] + q2[lc] - 2.0f * acc[mi][nj][3], 0.0f));
      int u = c + 8 * (r0 >> 4);
      ushort* p = Sb + (size_t)u * 1024 + r0;
      *(uint2*)p = make_uint2(pack2(vx, vy), pack2(vz, vw));
    }
}

// One block per batch, 3 waves:
//   wave0: full DTW, 16 rows/lane, 8-column macro-steps (191 macros, 2/phase).
//     Cross-lane: lane l's top row = shfl_up of lane l-1's bottom row, exchanged
//     ONCE per macro (8 bpermutes, consumed next macro -> huge slack).
//   wave1/2: stage 16 u-rows per phase into double-buffered LDS (8 rows each).
__global__ __launch_bounds__(192, 1) void dtw_kernel(const ushort* __restrict__ stream,
                                                     float* __restrict__ out) {
  __shared__ ushort buf[2][16][1024];  // 64 KB

  const int b    = blockIdx.x;
  const int tid  = threadIdx.x;
  const int wave = tid >> 6;
  const int lane = tid & 63;
  const ushort* Sb = stream + (size_t)b * UDIM_ * 1024;

  if (wave != 0) {
    // ---------------- loader waves ----------------
    auto loadPhase = [&](int q) {  // u-rows 16q..16q+15 -> buf[q&1]
      const int rb = (wave - 1) * 8;
#pragma unroll
      for (int i = 0; i < 8; ++i) {
        int j = 16 * q + rb + i;  // <= 1535 < UDIM_
        const ushort* sp = Sb + (size_t)j * 1024 + 8 * lane;
        uint4 a0 = *(const uint4*)sp;
        uint4 a1 = *(const uint4*)(sp + 512);
        *(uint4*)&buf[q & 1][rb + i][8 * lane] = a0;
        *(uint4*)&buf[q & 1][rb + i][8 * lane + 512] = a1;
      }
    };
    loadPhase(0);
    for (int p = 0; p < NPH_; ++p) {
      __syncthreads();
      if (p < NPH_ - 1) loadPhase(p + 1);
    }
    return;
  }

  // ---------------- compute wave ----------------
  const bool l0 = (lane == 0);
  float left[16];
#pragma unroll
  for (int r = 0; r < 16; ++r) left[r] = BIGV;
  float tops[8];
#pragma unroll
  for (int j = 0; j < 8; ++j) tops[j] = BIGV;
  float corner = l0 ? 0.0f : BIGV;
  float bot[8];
  float result = 0.0f;
  uint4 pre[2][2];

  for (int p = 0; p < NPH_; ++p) {
    __syncthreads();  // buf[p&1] holds u-rows 16p..16p+15
#pragma unroll
    for (int h = 0; h < 2; ++h) {
      const int m = 2 * p + h;
      if (m > 190) break;
      const bool act   = (m >= lane) && (m <= lane + 127);
      const bool first = (m == lane);
      const ushort(*lds)[1024] = buf[p & 1];
      const int rb = h * 8;  // u-row base within buffer

      if (first) {  // reset left boundary at activation (col -1 = inf)
#pragma unroll
        for (int r = 0; r < 16; ++r) left[r] = BIGV;
      }

      // prime 2-deep column ring
#pragma unroll
      for (int q = 0; q < 2; ++q) {
        pre[q][0] = *(const uint4*)&lds[rb + q][16 * lane];
        pre[q][1] = *(const uint4*)&lds[rb + q][16 * lane + 8];
      }

#pragma unroll
      for (int cc = 0; cc < 8; ++cc) {
        uint4 cw0 = pre[cc & 1][0];
        uint4 cw1 = pre[cc & 1][1];
        if (cc < 6) {
          pre[cc & 1][0] = *(const uint4*)&lds[rb + cc + 2][16 * lane];
          pre[cc & 1][1] = *(const uint4*)&lds[rb + cc + 2][16 * lane + 8];
        }
        float cv[16];
        cv[0]  = __uint_as_float(cw0.x << 16);
        cv[1]  = __uint_as_float(cw0.x & 0xFFFF0000u);
        cv[2]  = __uint_as_float(cw0.y << 16);
        cv[3]  = __uint_as_float(cw0.y & 0xFFFF0000u);
        cv[4]  = __uint_as_float(cw0.z << 16);
        cv[5]  = __uint_as_float(cw0.z & 0xFFFF0000u);
        cv[6]  = __uint_as_float(cw0.w << 16);
        cv[7]  = __uint_as_float(cw0.w & 0xFFFF0000u);
        cv[8]  = __uint_as_float(cw1.x << 16);
        cv[9]  = __uint_as_float(cw1.x & 0xFFFF0000u);
        cv[10] = __uint_as_float(cw1.y << 16);
        cv[11] = __uint_as_float(cw1.y & 0xFFFF0000u);
        cv[12] = __uint_as_float(cw1.z << 16);
        cv[13] = __uint_as_float(cw1.z & 0xFFFF0000u);
        cv[14] = __uint_as_float(cw1.w << 16);
        cv[15] = __uint_as_float(cw1.w & 0xFFFF0000u);

        // DP column: up = cur_{r-1} (this col), diag = left[r-1], left = left[r]
        float diag0 = (cc == 0) ? corner : tops[cc - 1];
        float cur = cv[0] + fminf(fminf(tops[cc], diag0), left[0]);
        float nl[16];
        nl[0] = cur;
#pragma unroll
        for (int r = 1; r < 16; ++r) {
          cur = cv[r] + fminf(fminf(cur, left[r - 1]), left[r]);  // v_min3 + v_add
          nl[r] = cur;
        }
#pragma unroll
        for (int r = 0; r < 16; ++r) left[r] = nl[r];
        bot[cc] = act ? cur : BIGV;  // only bot crosses lanes; left garbage is
                                     // reset at `first` for pre-active lanes
      }

      // macro epilogue: batch cross-lane exchange (consumed next macro)
      corner = tops[7];  // neighbor bottom at col C+7 = next macro's (0,0) diag
#pragma unroll
      for (int j = 0; j < 8; ++j) {
        float t = __shfl_up(bot[j], 1, 64);
        tops[j] = l0 ? BIGV : t;  // lane0: DP row-0 boundary is +inf
      }
      if (m == 190) result = bot[7];  // lane63, col 1023: D[1024][1024]
    }
  }
  if (lane == 63) out[b] = 1.0f / (1.0f + result * (1.0f / 2048.0f));
}

extern "C" void kernel_launch(void* const* d_in, const int* in_sizes, int n_in,
                              void* d_out, int out_size, void* d_ws, size_t ws_size,
                              hipStream_t stream_) {
  const float* s1 = (const float*)d_in[0];
  const float* s2 = (const float*)d_in[1];
  float* out = (float*)d_out;
  ushort* cws = (ushort*)d_ws;
  float* nrm = (float*)(cws + STREAM_US);

  norm_kernel<<<dim3((2 * B_ * L_) / 4), 256, 0, stream_>>>(s1, s2, nrm);
  cost_kernel<<<dim3(64, B_), 256, 0, stream_>>>(s1, s2, cws, nrm);
  dtw_kernel<<<dim3(B_), 192, 0, stream_>>>(cws, out);
}

// Round 11
// 226.825 us; speedup vs baseline: 1.3120x; 1.3120x over previous
//
#include <hip/hip_runtime.h>
#include <hip/hip_bf16.h>

#define BIGV 1.0e9f

static constexpr int B_ = 32;
static constexpr int L_ = 1024;
static constexpr int F_ = 128;
static constexpr int S_ = 2;          // in-wave lane stagger (columns)
static constexpr int UDIM_ = 1296;    // skewed u-rows per stream (1149 used + slack)
static constexpr int LAG_ = 160;      // wave1 local-step lag (10 phases)
static constexpr int NSEGL_ = 72;     // local phases per wave (1152 steps)
static constexpr int NSEGG_ = 82;     // global phases (1312 steps)
static constexpr size_t STREAM_US = (size_t)B_ * 2 * UDIM_ * 512;  // ushorts

typedef __attribute__((ext_vector_type(8))) short short8;
typedef __attribute__((ext_vector_type(4))) float f32x4;

__device__ __forceinline__ unsigned pack2(float x, float y) {
  union { float f; unsigned u; } a, b;
  a.f = x; b.f = y;
  unsigned lo = (a.u + 0x7FFFu + ((a.u >> 16) & 1u)) >> 16;
  unsigned hi = (b.u + 0x7FFFu + ((b.u >> 16) & 1u)) >> 16;
  return lo | (hi << 16);
}

// one wave per row of 128 floats; nrm[wid] = sum of squares
__global__ void norm_kernel(const float* __restrict__ s1, const float* __restrict__ s2,
                            float* __restrict__ nrm) {
  int gt   = blockIdx.x * blockDim.x + threadIdx.x;
  int wid  = gt >> 6;
  int lane = gt & 63;
  const float* src = (wid < B_ * L_) ? (s1 + (size_t)wid * F_)
                                     : (s2 + (size_t)(wid - B_ * L_) * F_);
  float2 v = ((const float2*)src)[lane];
  float s = v.x * v.x + v.y * v.y;
#pragma unroll
  for (int o = 32; o > 0; o >>= 1) s += __shfl_xor(s, o, 64);
  if (lane == 0) nrm[wid] = s;
}

// cost matrix -> bf16, two skewed streams per batch (one per dtw compute wave):
// global row r: w = r>>9, rl = r&511; element (r, col c) stored at
// stream[(b*2+w)][u = c + S_*(rl>>3)][rl]  (skew matches lane stagger S_).
__global__ __launch_bounds__(256) void cost_kernel(const float* __restrict__ s1,
                                                   const float* __restrict__ s2,
                                                   ushort* __restrict__ stream,
                                                   const float* __restrict__ nrm) {
  __shared__ short aL[128][136];
  __shared__ short bL[128][136];
  __shared__ float q1[128], q2[128];

  const int tid = threadIdx.x;
  const int b   = blockIdx.y;
  const int tc  = blockIdx.x & 7;
  const int tr  = blockIdx.x >> 3;

  const float* Ap = s1 + (size_t)b * L_ * F_ + (size_t)tr * 128 * F_;
  const float* Bp = s2 + (size_t)b * L_ * F_ + (size_t)tc * 128 * F_;

#pragma unroll 4
  for (int it = 0; it < 16; ++it) {
    int idx = it * 1024 + tid * 4;
    int r = idx >> 7, cc = idx & 127;
    float4 va = *(const float4*)(Ap + idx);
    float4 vb = *(const float4*)(Bp + idx);
    *(uint2*)&aL[r][cc] = make_uint2(pack2(va.x, va.y), pack2(va.z, va.w));
    *(uint2*)&bL[r][cc] = make_uint2(pack2(vb.x, vb.y), pack2(vb.z, vb.w));
  }
  if (tid < 128) q1[tid] = nrm[(size_t)b * L_ + tr * 128 + tid];
  else           q2[tid - 128] = nrm[(size_t)B_ * L_ + (size_t)b * L_ + tc * 128 + (tid - 128)];
  __syncthreads();

  const int wave = tid >> 6, lane = tid & 63, quad = lane >> 4, l16 = lane & 15;
  const int m0 = (wave >> 1) * 64, n0 = (wave & 1) * 64;

  f32x4 acc[4][4] = {};
#pragma unroll
  for (int kc = 0; kc < 4; ++kc) {
    short8 af[4], bf[4];
#pragma unroll
    for (int mi = 0; mi < 4; ++mi)
      af[mi] = *(const short8*)&aL[m0 + mi * 16 + l16][kc * 32 + quad * 8];
#pragma unroll
    for (int nj = 0; nj < 4; ++nj)
      bf[nj] = *(const short8*)&bL[n0 + nj * 16 + l16][kc * 32 + quad * 8];
#pragma unroll
    for (int mi = 0; mi < 4; ++mi)
#pragma unroll
      for (int nj = 0; nj < 4; ++nj)
        acc[mi][nj] = __builtin_amdgcn_mfma_f32_16x16x32_bf16(af[mi], bf[nj], acc[mi][nj], 0, 0, 0);
  }

  ushort* Sb = stream + (size_t)(b * 2) * UDIM_ * 512;
#pragma unroll
  for (int mi = 0; mi < 4; ++mi)
#pragma unroll
    for (int nj = 0; nj < 4; ++nj) {
      int lr0 = m0 + mi * 16 + quad * 4;
      int lc  = n0 + nj * 16 + l16;
      int r0  = tr * 128 + lr0;   // 4-aligned: rows r0..r0+3 share (rl>>3)
      int c   = tc * 128 + lc;
      float vx = sqrtf(fmaxf(q1[lr0 + 0] + q2[lc] - 2.0f * acc[mi][nj][0], 0.0f));
      float vy = sqrtf(fmaxf(q1[lr0 + 1] + q2[lc] - 2.0f * acc[mi][nj][1], 0.0f));
      float vz = sqrtf(fmaxf(q1[lr0 + 2] + q2[lc] - 2.0f * acc[mi][nj][2], 0.0f));
      float vw = sqrtf(fmaxf(q1[lr0 + 3] + q2[lc] - 2.0f * acc[mi][nj][3], 0.0f));
      int w  = r0 >> 9;
      int rl = r0 & 511;
      int u  = c + S_ * (rl >> 3);
      ushort* p = Sb + ((size_t)w * UDIM_ + u) * 512 + rl;
      *(uint2*)p = make_uint2(pack2(vx, vy), pack2(vz, vw));
    }
}

#define UNPACK_CV(cw, cv)                         \
  cv[0] = __uint_as_float((cw).x << 16);          \
  cv[1] = __uint_as_float((cw).x & 0xFFFF0000u);  \
  cv[2] = __uint_as_float((cw).y << 16);          \
  cv[3] = __uint_as_float((cw).y & 0xFFFF0000u);  \
  cv[4] = __uint_as_float((cw).z << 16);          \
  cv[5] = __uint_as_float((cw).z & 0xFFFF0000u);  \
  cv[6] = __uint_as_float((cw).w << 16);          \
  cv[7] = __uint_as_float((cw).w & 0xFFFF0000u);

#define CHAIN_BODY(head)                                            \
  {                                                                 \
    float cur = (head);                                             \
    float nl[8];                                                    \
    nl[0] = cur;                                                    \
    _Pragma("unroll") for (int r = 1; r < 8; ++r) {                 \
      cur = cv[r] + fminf(fminf(left[r - 1], left[r]), cur);        \
      nl[r] = cur;                                                  \
    }                                                               \
    _Pragma("unroll") for (int r = 0; r < 8; ++r) left[r] = nl[r];  \
    bot = nl[7];                                                    \
  }

// One block per batch, 4 waves (R9 structure, S=2 stagger):
//   wave0: DTW rows 0..511 (8 rows/lane); writes hand[] (batched b128 in fast phases)
//   wave1: DTW rows 512..1023, lag LAG_; reads hand[] via 4-deep register ring
//   wave2/3: loaders staging stream0/stream1 u-rows into double-buffered LDS segs
// S=2 ring algebra: up = lane-1 bot captured at step k-1 -> sh[(k+3)&3];
// diag = captured at k-2 -> sh[(k+2)&3]. (Same derivation reproduces R9's
// S=4 slots k&3 / (k+1)&3.)
__global__ __launch_bounds__(256, 1) void dtw_kernel(const ushort* __restrict__ stream,
                                                     float* __restrict__ out) {
  __shared__ ushort ldsA[2][16][512];  // 32 KB, wave0 stream
  __shared__ ushort ldsB[2][16][512];  // 32 KB, wave1 stream
  __shared__ float hand[1040];         // row-511 D values; +16 slack for unmasked prefetch

  const int b    = blockIdx.x;
  const int tid  = threadIdx.x;
  const int wave = tid >> 6;
  const int lane = tid & 63;

  if (wave >= 2) {
    // ---------------- loader waves ----------------
    const int ls = wave - 2;  // 0 -> stream A, 1 -> stream B
    const ushort* src = stream + (size_t)(b * 2 + ls) * UDIM_ * 512;
    auto loadSeg = [&](int g, int buf) {
      ushort(*dst)[512] = ls ? ldsB[buf] : ldsA[buf];
#pragma unroll
      for (int i = 0; i < 16; ++i) {
        const uint4* sp = (const uint4*)(src + (size_t)(g * 16 + i) * 512);
        *(uint4*)&dst[i][lane * 8] = sp[lane];
      }
    };
    if (ls == 0) loadSeg(0, 0);  // preload wave0 seg 0
    for (int n = 0; n < NSEGG_; ++n) {
      __syncthreads();
      int g = (ls == 0) ? (n + 1) : (n - 9);  // B: seg for phase n+1 = (n+1) - LAG/16
      if ((unsigned)g < (unsigned)NSEGL_) loadSeg(g, g & 1);
    }
    return;
  }

  // ---------------- compute waves ----------------
  const bool l0 = (lane == 0);
  float left[8];
#pragma unroll
  for (int r = 0; r < 8; ++r) left[r] = BIGV;
  float bot = BIGV;
  float sh[4] = {BIGV, BIGV, BIGV, BIGV};
  float hPrev = BIGV, result = 0.0f;
  float hRing[4];
  float hb[16];
  uint4 pre[4];

  for (int n = 0; n < NSEGG_; ++n) {
    __syncthreads();  // hand[] writes >=1 phase old visible; loader seg published
    const int sBase = 16 * n - (wave ? LAG_ : 0);
    if ((unsigned)sBase >= 1152u) continue;  // idle phase (barrier already hit)

    const ushort(*lds)[512] = wave ? ldsB[(sBase >> 4) & 1] : ldsA[(sBase >> 4) & 1];
#pragma unroll
    for (int i = 0; i < 4; ++i) pre[i] = *(const uint4*)&lds[i][lane * 8];

    // fast: every lane active for all 16 steps (lane63 started: sBase>=126+;
    // lane0 not finished: sBase+15 <= 1023)
    const bool fast = (sBase >= 128) & (sBase <= 1008);

    if (wave == 0) {
      if (fast) {
#pragma unroll
        for (int k = 0; k < 16; ++k) {
          float shN = __shfl_up(bot, 1, 64);
          uint4 cw = pre[k & 3];
          if (k < 12) pre[k & 3] = *(const uint4*)&lds[k + 4][lane * 8];
          float cv[8];
          UNPACK_CV(cw, cv)
          float dgT = l0 ? BIGV : sh[(k + 2) & 3];
          float upT = l0 ? BIGV : sh[(k + 3) & 3];
          CHAIN_BODY(cv[0] + fminf(fminf(dgT, upT), left[0]))
          sh[k & 3] = shN;
          hb[k] = bot;
        }
        if (lane == 63) {  // batched hand write: j = sBase-126 .. +15 (all valid)
          float4* hp = (float4*)&hand[sBase - 126];
          hp[0] = make_float4(hb[0], hb[1], hb[2], hb[3]);
          hp[1] = make_float4(hb[4], hb[5], hb[6], hb[7]);
          hp[2] = make_float4(hb[8], hb[9], hb[10], hb[11]);
          hp[3] = make_float4(hb[12], hb[13], hb[14], hb[15]);
        }
      } else {
#pragma unroll
        for (int k = 0; k < 16; ++k) {
          const int s = sBase + k;
          const int col = s - S_ * lane;
          float shN = __shfl_up(bot, 1, 64);
          uint4 cw = pre[k & 3];
          if (k < 12) pre[k & 3] = *(const uint4*)&lds[k + 4][lane * 8];
          float cv[8];
          UNPACK_CV(cw, cv)
          float dgT = l0 ? ((s == 0) ? 0.0f : BIGV) : sh[(k + 2) & 3];
          float upT = l0 ? BIGV : sh[(k + 3) & 3];
          bool act = ((unsigned)col < 1024u);
          float c0 = act ? cv[0] : BIGV;  // head-only mask; induction keeps
                                          // inactive-lane state >= ~1e9
          CHAIN_BODY(c0 + fminf(fminf(dgT, upT), left[0]))
          sh[k & 3] = shN;
          int j = s - 126;  // lane63's column this step
          if (lane == 63 && (unsigned)j < 1024u) hand[j] = bot;
        }
      }
    } else {
      if (fast) {
#pragma unroll
        for (int i = 0; i < 4; ++i) hRing[i] = hand[sBase + i];
#pragma unroll
        for (int k = 0; k < 16; ++k) {
          float shN = __shfl_up(bot, 1, 64);
          float hCur = hRing[k & 3];
          uint4 cw = pre[k & 3];
          if (k < 12) pre[k & 3] = *(const uint4*)&lds[k + 4][lane * 8];
          hRing[k & 3] = hand[sBase + k + 4];  // <= 1027 < 1040, in-bounds
          float cv[8];
          UNPACK_CV(cw, cv)
          float dgT = l0 ? hPrev : sh[(k + 2) & 3];
          float upT = l0 ? hCur : sh[(k + 3) & 3];
          CHAIN_BODY(cv[0] + fminf(fminf(dgT, upT), left[0]))
          sh[k & 3] = shN;
          hPrev = hCur;
        }
      } else {
#pragma unroll
        for (int i = 0; i < 4; ++i) hRing[i] = hand[(sBase + i) & 1023];
#pragma unroll
        for (int k = 0; k < 16; ++k) {
          const int s = sBase + k;
          const int col = s - S_ * lane;
          float shN = __shfl_up(bot, 1, 64);
          float hCur = hRing[k & 3];
          uint4 cw = pre[k & 3];
          if (k < 12) pre[k & 3] = *(const uint4*)&lds[k + 4][lane * 8];
          hRing[k & 3] = hand[(s + 4) & 1023];
          float cv[8];
          UNPACK_CV(cw, cv)
          float dgT = l0 ? ((s == 0) ? BIGV : hPrev) : sh[(k + 2) & 3];
          float upT = l0 ? hCur : sh[(k + 3) & 3];
          bool act = ((unsigned)col < 1024u);
          float c0 = act ? cv[0] : BIGV;
          CHAIN_BODY(c0 + fminf(fminf(dgT, upT), left[0]))
          sh[k & 3] = shN;
          hPrev = hCur;
          if (s == 1149) result = bot;  // lane63 at col 1023: D[1024][1024]
        }
      }
    }
  }
  if (wave == 1 && lane == 63) out[b] = 1.0f / (1.0f + result * (1.0f / 2048.0f));
}

extern "C" void kernel_launch(void* const* d_in, const int* in_sizes, int n_in,
                              void* d_out, int out_size, void* d_ws, size_t ws_size,
                              hipStream_t stream_) {
  const float* s1 = (const float*)d_in[0];
  const float* s2 = (const float*)d_in[1];
  float* out = (float*)d_out;
  ushort* cws = (ushort*)d_ws;
  float* nrm = (float*)(cws + STREAM_US);

  norm_kernel<<<dim3((2 * B_ * L_) / 4), 256, 0, stream_>>>(s1, s2, nrm);
  cost_kernel<<<dim3(64, B_), 256, 0, stream_>>>(s1, s2, cws, nrm);
  dtw_kernel<<<dim3(B_), 256, 0, stream_>>>(cws, out);
}